// Round 9
// baseline (6696.416 us; speedup 1.0000x reference)
//
#include <hip/hip_runtime.h>
#include <math.h>

#define B_ 512
#define E_ 256
#define H_ 512
#define V_ 4096
#define T_ 18
#define L_ 20
#define MARGIN_ 0.02

// ================= prep: cat fp64, embD fp64, curTok=SOS =================
__global__ __launch_bounds__(256) void kprep(const float* __restrict__ pa,
                                             const float* __restrict__ pb,
                                             const float* __restrict__ emb,
                                             double* __restrict__ cat,
                                             double* __restrict__ embD,
                                             int* __restrict__ curTok) {
  int idx = blockIdx.x * 256 + threadIdx.x;
  if (idx < 524288) {
    int b = idx >> 10, k = idx & 1023;
    cat[idx] = (double)((k < 512) ? pa[b * 512 + k] : pb[b * 512 + (k - 512)]);
  } else if (idx < 524288 + 1048576) {
    int e = idx - 524288;
    embD[e] = (double)emb[e];
  } else {
    int b = idx - 1572864;
    if (b < B_) curTok[b] = 1;   // SOS
  }
}

// ========= fp64 GEMM, 128x64 tile (MxN), 8x4/thread, split-K =========
// P[z][M,N] = A[M,K_z] (fp64) @ W[N,K_z]^T (fp32).
__global__ __launch_bounds__(256) void dgemm64(const double* __restrict__ A,
                                               const float* __restrict__ W,
                                               double* __restrict__ P,
                                               int N, int lda, int kPer) {
  __shared__ double As[16][130];
  __shared__ float  Bs[16][68];
  const int tid = threadIdx.x;
  const int tx = tid & 15, ty = tid >> 4;
  const int bn = blockIdx.x * 64, bm = blockIdx.y * 128;
  const int k0 = blockIdx.z * kPer;
  const size_t pOff = (size_t)blockIdx.z * (size_t)gridDim.y * 128 * N;
  const int kk0 = tid & 15;
  const int ra0 = (tid >> 4) * 8;
  const int cb0 = (tid >> 4) * 4;

  double acc[8][4] = {};
  for (int kb = 0; kb < kPer; kb += 16) {
#pragma unroll
    for (int q = 0; q < 8; ++q)
      As[kk0][ra0 + q] = A[(size_t)(bm + ra0 + q) * lda + k0 + kb + kk0];
#pragma unroll
    for (int q = 0; q < 4; ++q)
      Bs[kk0][cb0 + q] = W[(size_t)(bn + cb0 + q) * lda + k0 + kb + kk0];
    __syncthreads();
#pragma unroll
    for (int kk = 0; kk < 16; ++kk) {
      double a[8];
#pragma unroll
      for (int i = 0; i < 8; ++i) a[i] = As[kk][ty + 16 * i];
#pragma unroll
      for (int j = 0; j < 4; ++j) {
        double w = (double)Bs[kk][tx + 16 * j];
#pragma unroll
        for (int i = 0; i < 8; ++i) acc[i][j] = fma(a[i], w, acc[i][j]);
      }
    }
    __syncthreads();
  }
#pragma unroll
  for (int i = 0; i < 8; ++i) {
    size_t r = (size_t)(bm + ty + 16 * i);
#pragma unroll
    for (int j = 0; j < 4; ++j)
      P[pOff + r * N + bn + tx + 16 * j] = acc[i][j];
  }
}

// ========= fp32 GEMM, 128x64 tile, 8x4/thread, split-K (logits screen) ====
__global__ __launch_bounds__(256) void sgemm64(const float* __restrict__ A,
                                               const float* __restrict__ W,
                                               float* __restrict__ P,
                                               int N, int lda, int kPer) {
  __shared__ float As[16][132];
  __shared__ float Bs[16][68];
  const int tid = threadIdx.x;
  const int tx = tid & 15, ty = tid >> 4;
  const int bn = blockIdx.x * 64, bm = blockIdx.y * 128;
  const int k0 = blockIdx.z * kPer;
  const size_t pOff = (size_t)blockIdx.z * (size_t)gridDim.y * 128 * N;
  const int kk0 = tid & 15;
  const int ra0 = (tid >> 4) * 8;
  const int cb0 = (tid >> 4) * 4;

  float acc[8][4] = {};
  for (int kb = 0; kb < kPer; kb += 16) {
#pragma unroll
    for (int q = 0; q < 8; ++q)
      As[kk0][ra0 + q] = A[(size_t)(bm + ra0 + q) * lda + k0 + kb + kk0];
#pragma unroll
    for (int q = 0; q < 4; ++q)
      Bs[kk0][cb0 + q] = W[(size_t)(bn + cb0 + q) * lda + k0 + kb + kk0];
    __syncthreads();
#pragma unroll
    for (int kk = 0; kk < 16; ++kk) {
      float a[8];
#pragma unroll
      for (int i = 0; i < 8; ++i) a[i] = As[kk][ty + 16 * i];
#pragma unroll
      for (int j = 0; j < 4; ++j) {
        float w = Bs[kk][tx + 16 * j];
#pragma unroll
        for (int i = 0; i < 8; ++i) acc[i][j] = fmaf(a[i], w, acc[i][j]);
      }
    }
    __syncthreads();
  }
#pragma unroll
  for (int i = 0; i < 8; ++i) {
    size_t r = (size_t)(bm + ty + 16 * i);
#pragma unroll
    for (int j = 0; j < 4; ++j)
      P[pOff + r * N + bn + tx + 16 * j] = acc[i][j];
  }
}

// ======== h0 = sum of 8 partials + b_init; also fp32 copy ========
__global__ __launch_bounds__(256) void reduceH0(const double* __restrict__ parts,
                                                const float* __restrict__ binit,
                                                double* __restrict__ h,
                                                float* __restrict__ hF) {
  int i = blockIdx.x * 256 + threadIdx.x;   // < 262144
  double s = (double)binit[i & 511];
#pragma unroll
  for (int c = 0; c < 8; ++c) s += parts[(size_t)c * 262144 + i];
  h[i] = s;
  hF[i] = (float)s;
}

// ====== gates: sum 8 gh partials + gather giAll[curTok] + GRU update ======
__global__ __launch_bounds__(256) void gates64(const double* __restrict__ ghP,
                                               const double* __restrict__ giAll,
                                               const float* __restrict__ bih,
                                               const float* __restrict__ bhh,
                                               const int* __restrict__ curTok,
                                               double* __restrict__ h,
                                               float* __restrict__ hF) {
  int idx = blockIdx.x * 256 + threadIdx.x;   // < B_*H_
  int b = idx >> 9, j = idx & (H_ - 1);
  size_t base = (size_t)b * 1536;
  double gr = (double)bhh[j], gz = (double)bhh[512 + j], gn = (double)bhh[1024 + j];
#pragma unroll
  for (int s = 0; s < 8; ++s) {
    const double* p = ghP + (size_t)s * 786432 + base;
    gr += p[j]; gz += p[512 + j]; gn += p[1024 + j];
  }
  const double* gib = giAll + (size_t)curTok[b] * 1536;
  double ir  = gib[j]        + (double)bih[j];
  double iz  = gib[512 + j]  + (double)bih[512 + j];
  double inn = gib[1024 + j] + (double)bih[1024 + j];
  double r = 1.0 / (1.0 + exp(-(ir + gr)));
  double z = 1.0 / (1.0 + exp(-(iz + gz)));
  double n = tanh(inn + r * gn);
  double hn = (1.0 - z) * n + z * h[idx];
  h[idx] = hn;
  hF[idx] = (float)hn;
}

// ====== pickTok: fused screen + exact fallback (no atomics, deterministic) ==
// Phase 1: scores from fp32 GEMM partials (fp64-summed) + fp64 gumbel;
//          block argmax + count of candidates within MARGIN of max.
// If unique within margin -> accept (error bound ~5e-4 << MARGIN/2).
// Else -> exact fp64 rescore of the whole row (block-uniform branch).
__global__ __launch_bounds__(256) void pickTok(const float* __restrict__ loP,
                                               const double* __restrict__ h,
                                               const float* __restrict__ Wout,
                                               const float* __restrict__ bout,
                                               const float* __restrict__ u,  // step slice
                                               int* __restrict__ toks,
                                               int* __restrict__ curTok,
                                               int t) {
  int b = blockIdx.x, tid = threadIdx.x;
  const float* l0 = loP + (size_t)b * V_;
  const float* l1 = l0 + 2097152;
  const float* l2 = l0 + 4194304;
  const float* l3 = l0 + 6291456;
  const float* ub = u + (size_t)b * V_;
  double sloc[16];
  double best = -1e300; int bi = 0x7fffffff;
#pragma unroll
  for (int i = 0; i < 16; ++i) {
    int v = tid + 256 * i;
    double l = (double)l0[v] + (double)l1[v] + (double)l2[v] + (double)l3[v]
             + (double)bout[v];
    double s = l - log(-log((double)ub[v]));
    sloc[i] = s;
    if (s > best || (s == best && v < bi)) { best = s; bi = v; }
  }
  __shared__ double sv[256];
  __shared__ int    si[256];
  __shared__ int    sc[256];
  sv[tid] = best; si[tid] = bi;
  __syncthreads();
  for (int st = 128; st > 0; st >>= 1) {
    if (tid < st) {
      double ov = sv[tid + st]; int oi = si[tid + st];
      if (ov > sv[tid] || (ov == sv[tid] && oi < si[tid])) { sv[tid] = ov; si[tid] = oi; }
    }
    __syncthreads();
  }
  double smax = sv[0];
  int amax = si[0];
  int c = 0;
#pragma unroll
  for (int i = 0; i < 16; ++i) if (sloc[i] >= smax - MARGIN_) ++c;
  sc[tid] = c;
  __syncthreads();
  for (int st = 128; st > 0; st >>= 1) {
    if (tid < st) sc[tid] += sc[tid + st];
    __syncthreads();
  }
  int tok;
  if (sc[0] == 1) {
    tok = amax;                                  // provably exact
  } else {                                       // rare: full fp64 row rescore
    const double* hb = h + (size_t)b * H_;
    best = -1e300; bi = 0x7fffffff;
    for (int i = 0; i < 16; ++i) {
      int v = tid + 256 * i;
      const float* wr = Wout + (size_t)v * H_;
      double dot = 0.0;
      for (int k = 0; k < H_; ++k) dot = fma(hb[k], (double)wr[k], dot);
      double s = dot + (double)bout[v] - log(-log((double)ub[v]));
      if (s > best || (s == best && v < bi)) { best = s; bi = v; }
    }
    sv[tid] = best; si[tid] = bi;
    __syncthreads();
    for (int st = 128; st > 0; st >>= 1) {
      if (tid < st) {
        double ov = sv[tid + st]; int oi = si[tid + st];
        if (ov > sv[tid] || (ov == sv[tid] && oi < si[tid])) { sv[tid] = ov; si[tid] = oi; }
      }
      __syncthreads();
    }
    tok = si[0];
  }
  if (tid == 0) { toks[t * B_ + b] = tok; curTok[b] = tok; }
}

// ============== final: zero + one-hot scatter + SOS/EOS, fp32 ==============
__global__ __launch_bounds__(256) void kfinal32(float* __restrict__ out,
                                                const int* __restrict__ toks) {
  size_t c = (size_t)blockIdx.x * 256 + threadIdx.x;   // one float4
  size_t e0 = c * 4;
  int v0 = (int)(e0 & (size_t)(V_ - 1));
  size_t row = e0 >> 12;                               // b*L + p
  int p = (int)(row % L_);
  int b = (int)(row / L_);
  int tok;
  if (p == 0)           tok = 1;                       // SOS
  else if (p == L_ - 1) tok = 2;                       // EOS
  else                  tok = toks[(p - 1) * B_ + b];
  float4 val = make_float4(0.f, 0.f, 0.f, 0.f);
  int d = tok - v0;
  if (d >= 0 && d < 4) {
    if (d == 0) val.x = 1.f; else if (d == 1) val.y = 1.f;
    else if (d == 2) val.z = 1.f; else val.w = 1.f;
  }
  reinterpret_cast<float4*>(out)[c] = val;
}

// ---------------- environment markers ----------------
__global__ void kmark_ws(float* out) {
  if (threadIdx.x == 0) out[0] = 16.0f;
}
__global__ void kmark_resolver(float* out) {
  if (threadIdx.x == 0) out[2] = 11.0f;
}

// ================================ launch ================================
extern "C" void kernel_launch(void* const* d_in, const int* in_sizes, int n_in,
                              void* d_out, int out_size, void* d_ws, size_t ws_size,
                              hipStream_t stream) {
  static const int EXPECT[12] = {262144, 262144, 524288, 512, 393216, 786432,
                                 1536, 1536, 2097152, 4096, 1048576, 37748736};
  const float* R[12];
  bool resolved = (n_in == 12);
  if (resolved) {
    bool used[12] = {};
    for (int i = 0; i < 12; ++i) {
      int f = -1;
      for (int j = 0; j < 12; ++j)
        if (!used[j] && in_sizes[j] == EXPECT[i]) { f = j; break; }
      if (f < 0) { resolved = false; break; }
      used[f] = true;
      R[i] = (const float*)d_in[f];
    }
  }
  if (!resolved)
    for (int i = 0; i < 12 && i < n_in; ++i) R[i] = (const float*)d_in[i];

  const float *pa = R[0], *pb = R[1], *Winit = R[2], *binit = R[3],
              *Wih = R[4], *Whh = R[5], *bih = R[6], *bhh = R[7],
              *Wout = R[8], *bout = R[9], *emb = R[10], *ug = R[11];
  float* out = (float*)d_out;

  const size_t TOK_BYTES = (size_t)T_ * B_ * sizeof(int);   // 36864
  if (ws_size < TOK_BYTES) { kmark_ws<<<1, 64, 0, stream>>>(out); return; }
  int* toks = (int*)d_ws;

  // curTok in d_out tail (rebuilt by kfinal32 at the very end)
  size_t out_bytes = (size_t)out_size * 4;
  int* curTok = (int*)((char*)d_out + out_bytes - 2048);

  // scratch: h(2MB) | giAll(50.3MB) | ghP 8 chunks(50.3MB) | loP32 4 chunks(33.6MB)
  //          | hF(1MB)  -> total 137.4 MB
  const size_t SC_BYTES = 137363456;
  double* sc;
  if (ws_size >= 40960 + SC_BYTES) {
    sc = (double*)((char*)d_ws + 40960);
  } else {
    sc = (double*)d_out;   // head of 167.8 MB out; kfinal32 rebuilds last
  }
  double* h      = sc;                          // 262,144 dbl
  double* giAll  = sc + 262144;                 // 6,291,456 dbl
  double* ghP    = sc + 6553600;                // 6,291,456 dbl (8 chunks)
  float*  loP32  = (float*)(sc + 12845056);     // 8,388,608 f32 (4 chunks)
  float*  hF     = loP32 + 8388608;             // 262,144 f32
  double* embD   = ghP;                         // 1,048,576 dbl (pre-loop only)
  double* cat    = (double*)loP32;              // 524,288 dbl  (pre-loop only)
  double* h0P    = cat + 524288;                // 8 x 262,144 dbl (pre-loop only)

  // ---- setup ----
  kprep<<<6146, 256, 0, stream>>>(pa, pb, emb, cat, embD, curTok);
  // h0 partials: cat[512,1024] @ Winit[512,1024]^T, split-K=8
  dgemm64<<<dim3(8, 4, 8), 256, 0, stream>>>(cat, Winit, h0P, 512, 1024, 128);
  reduceH0<<<1024, 256, 0, stream>>>(h0P, binit, h, hF);
  // giAll = embD[4096,256] @ Wih[1536,256]^T (fp64)
  dgemm64<<<dim3(24, 32, 1), 256, 0, stream>>>(embD, Wih, giAll, 1536, 256, 256);

  // ---- decode loop ----
  for (int t = 0; t < T_; ++t) {
    // ghP = h[512,512] @ Whh[1536,512]^T fp64, split-K=8
    dgemm64<<<dim3(24, 4, 8), 256, 0, stream>>>(h, Whh, ghP, 1536, 512, 64);
    gates64<<<1024, 256, 0, stream>>>(ghP, giAll, bih, bhh, curTok, h, hF);
    // loP32 = hF[512,512] @ Wout[4096,512]^T fp32, split-K=4
    sgemm64<<<dim3(64, 4, 4), 256, 0, stream>>>(hF, Wout, loP32, 4096, 512, 128);
    pickTok<<<512, 256, 0, stream>>>(loP32, h, Wout, bout,
                                     ug + (size_t)t * B_ * V_, toks, curTok, t);
  }

  // ---- assemble fp32 output ----
  kfinal32<<<40960, 256, 0, stream>>>(out, toks);
  if (!resolved) kmark_resolver<<<1, 64, 0, stream>>>(out);
}

// Round 10
// 1966.281 us; speedup vs baseline: 3.4056x; 3.4056x over previous
//
#include <hip/hip_runtime.h>
#include <math.h>

#define B_ 512
#define E_ 256
#define H_ 512
#define V_ 4096
#define T_ 18
#define L_ 20
#define MARGIN_ 0.02
#define CCAP_ 64

// ================= prep: cat fp64, embD fp64, curTok=SOS =================
__global__ __launch_bounds__(256) void kprep(const float* __restrict__ pa,
                                             const float* __restrict__ pb,
                                             const float* __restrict__ emb,
                                             double* __restrict__ cat,
                                             double* __restrict__ embD,
                                             int* __restrict__ curTok) {
  int idx = blockIdx.x * 256 + threadIdx.x;
  if (idx < 524288) {
    int b = idx >> 10, k = idx & 1023;
    cat[idx] = (double)((k < 512) ? pa[b * 512 + k] : pb[b * 512 + (k - 512)]);
  } else if (idx < 524288 + 1048576) {
    int e = idx - 524288;
    embD[e] = (double)emb[e];
  } else {
    int b = idx - 1572864;
    if (b < B_) curTok[b] = 1;   // SOS
  }
}

// ========= fp64 GEMM, 128x64 tile (MxN), 8x4/thread, split-K =========
// P[z][M,N] = A[M,K_z] (fp64) @ W[N,K_z]^T (fp32).
__global__ __launch_bounds__(256) void dgemm64(const double* __restrict__ A,
                                               const float* __restrict__ W,
                                               double* __restrict__ P,
                                               int N, int lda, int kPer) {
  __shared__ double As[16][130];
  __shared__ float  Bs[16][68];
  const int tid = threadIdx.x;
  const int tx = tid & 15, ty = tid >> 4;
  const int bn = blockIdx.x * 64, bm = blockIdx.y * 128;
  const int k0 = blockIdx.z * kPer;
  const size_t pOff = (size_t)blockIdx.z * (size_t)gridDim.y * 128 * N;
  const int kk0 = tid & 15;
  const int ra0 = (tid >> 4) * 8;
  const int cb0 = (tid >> 4) * 4;

  double acc[8][4] = {};
  for (int kb = 0; kb < kPer; kb += 16) {
#pragma unroll
    for (int q = 0; q < 8; ++q)
      As[kk0][ra0 + q] = A[(size_t)(bm + ra0 + q) * lda + k0 + kb + kk0];
#pragma unroll
    for (int q = 0; q < 4; ++q)
      Bs[kk0][cb0 + q] = W[(size_t)(bn + cb0 + q) * lda + k0 + kb + kk0];
    __syncthreads();
#pragma unroll
    for (int kk = 0; kk < 16; ++kk) {
      double a[8];
#pragma unroll
      for (int i = 0; i < 8; ++i) a[i] = As[kk][ty + 16 * i];
#pragma unroll
      for (int j = 0; j < 4; ++j) {
        double w = (double)Bs[kk][tx + 16 * j];
#pragma unroll
        for (int i = 0; i < 8; ++i) acc[i][j] = fma(a[i], w, acc[i][j]);
      }
    }
    __syncthreads();
  }
#pragma unroll
  for (int i = 0; i < 8; ++i) {
    size_t r = (size_t)(bm + ty + 16 * i);
#pragma unroll
    for (int j = 0; j < 4; ++j)
      P[pOff + r * N + bn + tx + 16 * j] = acc[i][j];
  }
}

// ========= fp32 GEMM, 128x64 tile, 8x4/thread, split-K (logits screen) ====
__global__ __launch_bounds__(256) void sgemm64(const float* __restrict__ A,
                                               const float* __restrict__ W,
                                               float* __restrict__ P,
                                               int N, int lda, int kPer) {
  __shared__ float As[16][132];
  __shared__ float Bs[16][68];
  const int tid = threadIdx.x;
  const int tx = tid & 15, ty = tid >> 4;
  const int bn = blockIdx.x * 64, bm = blockIdx.y * 128;
  const int k0 = blockIdx.z * kPer;
  const size_t pOff = (size_t)blockIdx.z * (size_t)gridDim.y * 128 * N;
  const int kk0 = tid & 15;
  const int ra0 = (tid >> 4) * 8;
  const int cb0 = (tid >> 4) * 4;

  float acc[8][4] = {};
  for (int kb = 0; kb < kPer; kb += 16) {
#pragma unroll
    for (int q = 0; q < 8; ++q)
      As[kk0][ra0 + q] = A[(size_t)(bm + ra0 + q) * lda + k0 + kb + kk0];
#pragma unroll
    for (int q = 0; q < 4; ++q)
      Bs[kk0][cb0 + q] = W[(size_t)(bn + cb0 + q) * lda + k0 + kb + kk0];
    __syncthreads();
#pragma unroll
    for (int kk = 0; kk < 16; ++kk) {
      float a[8];
#pragma unroll
      for (int i = 0; i < 8; ++i) a[i] = As[kk][ty + 16 * i];
#pragma unroll
      for (int j = 0; j < 4; ++j) {
        float w = Bs[kk][tx + 16 * j];
#pragma unroll
        for (int i = 0; i < 8; ++i) acc[i][j] = fmaf(a[i], w, acc[i][j]);
      }
    }
    __syncthreads();
  }
#pragma unroll
  for (int i = 0; i < 8; ++i) {
    size_t r = (size_t)(bm + ty + 16 * i);
#pragma unroll
    for (int j = 0; j < 4; ++j)
      P[pOff + r * N + bn + tx + 16 * j] = acc[i][j];
  }
}

// ======== h0 = sum of 8 partials + b_init; also fp32 copy ========
__global__ __launch_bounds__(256) void reduceH0(const double* __restrict__ parts,
                                                const float* __restrict__ binit,
                                                double* __restrict__ h,
                                                float* __restrict__ hF) {
  int i = blockIdx.x * 256 + threadIdx.x;   // < 262144
  double s = (double)binit[i & 511];
#pragma unroll
  for (int c = 0; c < 8; ++c) s += parts[(size_t)c * 262144 + i];
  h[i] = s;
  hF[i] = (float)s;
}

// ====== gates: sum 8 gh partials + gather giAll[curTok] + GRU update ======
__global__ __launch_bounds__(256) void gates64(const double* __restrict__ ghP,
                                               const double* __restrict__ giAll,
                                               const float* __restrict__ bih,
                                               const float* __restrict__ bhh,
                                               const int* __restrict__ curTok,
                                               double* __restrict__ h,
                                               float* __restrict__ hF) {
  int idx = blockIdx.x * 256 + threadIdx.x;   // < B_*H_
  int b = idx >> 9, j = idx & (H_ - 1);
  size_t base = (size_t)b * 1536;
  double gr = (double)bhh[j], gz = (double)bhh[512 + j], gn = (double)bhh[1024 + j];
#pragma unroll
  for (int s = 0; s < 8; ++s) {
    const double* p = ghP + (size_t)s * 786432 + base;
    gr += p[j]; gz += p[512 + j]; gn += p[1024 + j];
  }
  const double* gib = giAll + (size_t)curTok[b] * 1536;
  double ir  = gib[j]        + (double)bih[j];
  double iz  = gib[512 + j]  + (double)bih[512 + j];
  double inn = gib[1024 + j] + (double)bih[1024 + j];
  double r = 1.0 / (1.0 + exp(-(ir + gr)));
  double z = 1.0 / (1.0 + exp(-(iz + gz)));
  double n = tanh(inn + r * gn);
  double hn = (1.0 - z) * n + z * h[idx];
  h[idx] = hn;
  hF[idx] = (float)hn;
}

// ====== pickTok: screen + candidate-only exact rescore (deterministic) ======
// Phase 1: scores = fp64 sum of 4 fp32 GEMM partials + bias + fp64 gumbel.
// Unique-within-margin -> accept. Else collect in-margin candidates (prefix
// scan, no atomics) and rescore ONLY those with cooperative fp64 dots.
__global__ __launch_bounds__(256) void pickTok(const float* __restrict__ loP,
                                               const double* __restrict__ h,
                                               const float* __restrict__ Wout,
                                               const float* __restrict__ bout,
                                               const float* __restrict__ u,  // step slice
                                               int* __restrict__ toks,
                                               int* __restrict__ curTok,
                                               int t) {
  int b = blockIdx.x, tid = threadIdx.x;
  const float* l0 = loP + (size_t)b * V_;
  const float* l1 = l0 + 2097152;
  const float* l2 = l0 + 4194304;
  const float* l3 = l0 + 6291456;
  const float* ub = u + (size_t)b * V_;
  double sloc[16];
  double best = -1e300; int bi = 0x7fffffff;
#pragma unroll
  for (int i = 0; i < 16; ++i) {
    int v = tid + 256 * i;
    double l = (double)l0[v] + (double)l1[v] + (double)l2[v] + (double)l3[v]
             + (double)bout[v];
    double s = l - log(-log((double)ub[v]));
    sloc[i] = s;
    if (s > best) { best = s; bi = v; }   // per-thread v ascending: > = first occ.
  }
  __shared__ double sv[256];
  __shared__ int    si[256];
  __shared__ int    pre[256];
  __shared__ int    candV[CCAP_];
  __shared__ double bestS;
  __shared__ int    bestV;
  sv[tid] = best; si[tid] = bi;
  __syncthreads();
  for (int st = 128; st > 0; st >>= 1) {
    if (tid < st) {
      double ov = sv[tid + st]; int oi = si[tid + st];
      if (ov > sv[tid] || (ov == sv[tid] && oi < si[tid])) { sv[tid] = ov; si[tid] = oi; }
    }
    __syncthreads();
  }
  double smax = sv[0];
  int amax = si[0];
  __syncthreads();                     // sv/si reused below
  // collect in-margin candidates, deterministic order
  int c = 0; int lv[16];
#pragma unroll
  for (int i = 0; i < 16; ++i)
    if (sloc[i] >= smax - MARGIN_) { if (c < 16) lv[c] = tid + 256 * i; ++c; }
  pre[tid] = c;
  __syncthreads();
  for (int off = 1; off < 256; off <<= 1) {          // Hillis-Steele inclusive scan
    int vv = (tid >= off) ? pre[tid - off] : 0;
    __syncthreads();
    pre[tid] += vv;
    __syncthreads();
  }
  int tot = pre[255];
  int base = pre[tid] - c;
  if (tot <= CCAP_)
    for (int q = 0; q < c; ++q) candV[base + q] = lv[q];
  __syncthreads();
  int tok;
  if (tot == 1) {
    tok = amax;                                       // provably exact
  } else if (tot <= CCAP_) {
    // cooperative fp64 rescore of each candidate (typically 2-3)
    const double* hb = h + (size_t)b * H_;
    if (tid == 0) { bestS = -1e300; bestV = 0x7fffffff; }
    __syncthreads();
    for (int ci = 0; ci < tot; ++ci) {
      int v = candV[ci];
      const float* wr = Wout + (size_t)v * H_;
      double p = fma(hb[tid], (double)wr[tid], 0.0);
      p = fma(hb[tid + 256], (double)wr[tid + 256], p);
      sv[tid] = p;
      __syncthreads();
      for (int st = 128; st > 0; st >>= 1) {
        if (tid < st) sv[tid] += sv[tid + st];
        __syncthreads();
      }
      if (tid == 0) {
        double s = sv[0] + (double)bout[v] - log(-log((double)ub[v]));
        if (s > bestS || (s == bestS && v < bestV)) { bestS = s; bestV = v; }
      }
      __syncthreads();
    }
    tok = bestV;
  } else {
    // unreachable safety net: full-row fp64 rescore
    const double* hb = h + (size_t)b * H_;
    best = -1e300; bi = 0x7fffffff;
    for (int i = 0; i < 16; ++i) {
      int v = tid + 256 * i;
      const float* wr = Wout + (size_t)v * H_;
      double dot = 0.0;
      for (int k = 0; k < H_; ++k) dot = fma(hb[k], (double)wr[k], dot);
      double s = dot + (double)bout[v] - log(-log((double)ub[v]));
      if (s > best) { best = s; bi = v; }
    }
    sv[tid] = best; si[tid] = bi;
    __syncthreads();
    for (int st = 128; st > 0; st >>= 1) {
      if (tid < st) {
        double ov = sv[tid + st]; int oi = si[tid + st];
        if (ov > sv[tid] || (ov == sv[tid] && oi < si[tid])) { sv[tid] = ov; si[tid] = oi; }
      }
      __syncthreads();
    }
    tok = si[0];
  }
  if (tid == 0) { toks[t * B_ + b] = tok; curTok[b] = tok; }
}

// ============== final: zero + one-hot scatter + SOS/EOS, fp32 ==============
__global__ __launch_bounds__(256) void kfinal32(float* __restrict__ out,
                                                const int* __restrict__ toks) {
  size_t c = (size_t)blockIdx.x * 256 + threadIdx.x;   // one float4
  size_t e0 = c * 4;
  int v0 = (int)(e0 & (size_t)(V_ - 1));
  size_t row = e0 >> 12;                               // b*L + p
  int p = (int)(row % L_);
  int b = (int)(row / L_);
  int tok;
  if (p == 0)           tok = 1;                       // SOS
  else if (p == L_ - 1) tok = 2;                       // EOS
  else                  tok = toks[(p - 1) * B_ + b];
  float4 val = make_float4(0.f, 0.f, 0.f, 0.f);
  int d = tok - v0;
  if (d >= 0 && d < 4) {
    if (d == 0) val.x = 1.f; else if (d == 1) val.y = 1.f;
    else if (d == 2) val.z = 1.f; else val.w = 1.f;
  }
  reinterpret_cast<float4*>(out)[c] = val;
}

// ---------------- environment markers ----------------
__global__ void kmark_ws(float* out) {
  if (threadIdx.x == 0) out[0] = 16.0f;
}
__global__ void kmark_resolver(float* out) {
  if (threadIdx.x == 0) out[2] = 11.0f;
}

// ================================ launch ================================
extern "C" void kernel_launch(void* const* d_in, const int* in_sizes, int n_in,
                              void* d_out, int out_size, void* d_ws, size_t ws_size,
                              hipStream_t stream) {
  static const int EXPECT[12] = {262144, 262144, 524288, 512, 393216, 786432,
                                 1536, 1536, 2097152, 4096, 1048576, 37748736};
  const float* R[12];
  bool resolved = (n_in == 12);
  if (resolved) {
    bool used[12] = {};
    for (int i = 0; i < 12; ++i) {
      int f = -1;
      for (int j = 0; j < 12; ++j)
        if (!used[j] && in_sizes[j] == EXPECT[i]) { f = j; break; }
      if (f < 0) { resolved = false; break; }
      used[f] = true;
      R[i] = (const float*)d_in[f];
    }
  }
  if (!resolved)
    for (int i = 0; i < 12 && i < n_in; ++i) R[i] = (const float*)d_in[i];

  const float *pa = R[0], *pb = R[1], *Winit = R[2], *binit = R[3],
              *Wih = R[4], *Whh = R[5], *bih = R[6], *bhh = R[7],
              *Wout = R[8], *bout = R[9], *emb = R[10], *ug = R[11];
  float* out = (float*)d_out;

  const size_t TOK_BYTES = (size_t)T_ * B_ * sizeof(int);   // 36864
  if (ws_size < TOK_BYTES) { kmark_ws<<<1, 64, 0, stream>>>(out); return; }
  int* toks = (int*)d_ws;

  // curTok in d_out tail (rebuilt by kfinal32 at the very end)
  size_t out_bytes = (size_t)out_size * 4;
  int* curTok = (int*)((char*)d_out + out_bytes - 2048);

  // scratch: h(2MB) | giAll(50.3MB) | ghP 8 chunks(50.3MB) | loP32 4 chunks(33.6MB)
  //          | hF(1MB)  -> total 137.4 MB
  const size_t SC_BYTES = 137363456;
  double* sc;
  if (ws_size >= 40960 + SC_BYTES) {
    sc = (double*)((char*)d_ws + 40960);
  } else {
    sc = (double*)d_out;   // head of 167.8 MB out; kfinal32 rebuilds last
  }
  double* h      = sc;                          // 262,144 dbl
  double* giAll  = sc + 262144;                 // 6,291,456 dbl
  double* ghP    = sc + 6553600;                // 6,291,456 dbl (8 chunks)
  float*  loP32  = (float*)(sc + 12845056);     // 8,388,608 f32 (4 chunks)
  float*  hF     = loP32 + 8388608;             // 262,144 f32
  double* embD   = ghP;                         // 1,048,576 dbl (pre-loop only)
  double* cat    = (double*)loP32;              // 524,288 dbl  (pre-loop only)
  double* h0P    = cat + 524288;                // 8 x 262,144 dbl (pre-loop only)

  // ---- setup ----
  kprep<<<6146, 256, 0, stream>>>(pa, pb, emb, cat, embD, curTok);
  // h0 partials: cat[512,1024] @ Winit[512,1024]^T, split-K=8
  dgemm64<<<dim3(8, 4, 8), 256, 0, stream>>>(cat, Winit, h0P, 512, 1024, 128);
  reduceH0<<<1024, 256, 0, stream>>>(h0P, binit, h, hF);
  // giAll = embD[4096,256] @ Wih[1536,256]^T (fp64)
  dgemm64<<<dim3(24, 32, 1), 256, 0, stream>>>(embD, Wih, giAll, 1536, 256, 256);

  // ---- decode loop ----
  for (int t = 0; t < T_; ++t) {
    // ghP = h[512,512] @ Whh[1536,512]^T fp64, split-K=8
    dgemm64<<<dim3(24, 4, 8), 256, 0, stream>>>(h, Whh, ghP, 1536, 512, 64);
    gates64<<<1024, 256, 0, stream>>>(ghP, giAll, bih, bhh, curTok, h, hF);
    // loP32 = hF[512,512] @ Wout[4096,512]^T fp32, split-K=4
    sgemm64<<<dim3(64, 4, 4), 256, 0, stream>>>(hF, Wout, loP32, 4096, 512, 128);
    pickTok<<<512, 256, 0, stream>>>(loP32, h, Wout, bout,
                                     ug + (size_t)t * B_ * V_, toks, curTok, t);
  }

  // ---- assemble fp32 output ----
  kfinal32<<<40960, 256, 0, stream>>>(out, toks);
  if (!resolved) kmark_resolver<<<1, 64, 0, stream>>>(out);
}

// Round 11
// 1677.248 us; speedup vs baseline: 3.9925x; 1.1723x over previous
//
#include <hip/hip_runtime.h>
#include <math.h>

#define B_ 512
#define E_ 256
#define H_ 512
#define V_ 4096
#define T_ 18
#define L_ 20
#define MARGIN_ 0.02
#define CCAP_ 64

// ================= prep: cat fp32 + curTok=SOS =================
__global__ __launch_bounds__(256) void kprep32(const float* __restrict__ pa,
                                               const float* __restrict__ pb,
                                               float* __restrict__ cat,
                                               int* __restrict__ curTok) {
  int idx = blockIdx.x * 256 + threadIdx.x;
  if (idx < 524288) {
    int b = idx >> 10, k = idx & 1023;
    cat[idx] = (k < 512) ? pa[b * 512 + k] : pb[b * 512 + (k - 512)];
  } else {
    int b = idx - 524288;
    if (b < B_) curTok[b] = 1;   // SOS
  }
}

// ========= fp32 GEMM, 128x64 tile (MxN), 8x4/thread, split-K =========
// P[z][M,N] = A[M,K_z] @ W[N,K_z]^T  (all fp32). No bias.
// grid (N/64, M/128, S); lda = full K; kPer = K/S (multiple of 16).
__global__ __launch_bounds__(256) void sgemm64(const float* __restrict__ A,
                                               const float* __restrict__ W,
                                               float* __restrict__ P,
                                               int N, int lda, int kPer) {
  __shared__ float As[16][132];
  __shared__ float Bs[16][68];
  const int tid = threadIdx.x;
  const int tx = tid & 15, ty = tid >> 4;
  const int bn = blockIdx.x * 64, bm = blockIdx.y * 128;
  const int k0 = blockIdx.z * kPer;
  const size_t pOff = (size_t)blockIdx.z * (size_t)gridDim.y * 128 * N;
  const int kk0 = tid & 15;
  const int ra0 = (tid >> 4) * 8;
  const int cb0 = (tid >> 4) * 4;

  float acc[8][4] = {};
  for (int kb = 0; kb < kPer; kb += 16) {
#pragma unroll
    for (int q = 0; q < 8; ++q)
      As[kk0][ra0 + q] = A[(size_t)(bm + ra0 + q) * lda + k0 + kb + kk0];
#pragma unroll
    for (int q = 0; q < 4; ++q)
      Bs[kk0][cb0 + q] = W[(size_t)(bn + cb0 + q) * lda + k0 + kb + kk0];
    __syncthreads();
#pragma unroll
    for (int kk = 0; kk < 16; ++kk) {
      float a[8];
#pragma unroll
      for (int i = 0; i < 8; ++i) a[i] = As[kk][ty + 16 * i];
#pragma unroll
      for (int j = 0; j < 4; ++j) {
        float w = Bs[kk][tx + 16 * j];
#pragma unroll
        for (int i = 0; i < 8; ++i) acc[i][j] = fmaf(a[i], w, acc[i][j]);
      }
    }
    __syncthreads();
  }
#pragma unroll
  for (int i = 0; i < 8; ++i) {
    size_t r = (size_t)(bm + ty + 16 * i);
#pragma unroll
    for (int j = 0; j < 4; ++j)
      P[pOff + r * N + bn + tx + 16 * j] = acc[i][j];
  }
}

// ======== h0 = sum of 8 partials + b_init (fp64 sum, fp32 out) ========
__global__ __launch_bounds__(256) void reduceH0(const float* __restrict__ parts,
                                                const float* __restrict__ binit,
                                                float* __restrict__ h) {
  int i = blockIdx.x * 256 + threadIdx.x;   // < 262144
  double s = (double)binit[i & 511];
#pragma unroll
  for (int c = 0; c < 8; ++c) s += (double)parts[(size_t)c * 262144 + i];
  h[i] = (float)s;
}

// ====== gates: sum 16 gh partials + gather 2 giAll partials + GRU update ====
// (internal math in fp64 for minimal added noise; h stored fp32)
__global__ __launch_bounds__(256) void gates32(const float* __restrict__ ghP,
                                               const float* __restrict__ giP,
                                               const float* __restrict__ bih,
                                               const float* __restrict__ bhh,
                                               const int* __restrict__ curTok,
                                               float* __restrict__ h) {
  int idx = blockIdx.x * 256 + threadIdx.x;   // < B_*H_
  int b = idx >> 9, j = idx & (H_ - 1);
  size_t base = (size_t)b * 1536;
  double gr = (double)bhh[j], gz = (double)bhh[512 + j], gn = (double)bhh[1024 + j];
#pragma unroll
  for (int s = 0; s < 16; ++s) {
    const float* p = ghP + (size_t)s * 786432 + base;
    gr += (double)p[j]; gz += (double)p[512 + j]; gn += (double)p[1024 + j];
  }
  const float* g0 = giP + (size_t)curTok[b] * 1536;
  const float* g1 = g0 + 6291456;
  double ir  = (double)g0[j]        + (double)g1[j]        + (double)bih[j];
  double iz  = (double)g0[512 + j]  + (double)g1[512 + j]  + (double)bih[512 + j];
  double inn = (double)g0[1024 + j] + (double)g1[1024 + j] + (double)bih[1024 + j];
  double r = 1.0 / (1.0 + exp(-(ir + gr)));
  double z = 1.0 / (1.0 + exp(-(iz + gz)));
  double n = tanh(inn + r * gn);
  h[idx] = (float)((1.0 - z) * n + z * (double)h[idx]);
}

// ====== pickTok: screen + candidate-only fp64 rescore (deterministic) ======
__global__ __launch_bounds__(256) void pickTok(const float* __restrict__ loP,
                                               const float* __restrict__ h,
                                               const float* __restrict__ Wout,
                                               const float* __restrict__ bout,
                                               const float* __restrict__ u,  // step slice
                                               int* __restrict__ toks,
                                               int* __restrict__ curTok,
                                               int t) {
  int b = blockIdx.x, tid = threadIdx.x;
  const float* l0 = loP + (size_t)b * V_;
  const float* l1 = l0 + 2097152;
  const float* l2 = l0 + 4194304;
  const float* l3 = l0 + 6291456;
  const float* ub = u + (size_t)b * V_;
  double sloc[16];
  double best = -1e300; int bi = 0x7fffffff;
#pragma unroll
  for (int i = 0; i < 16; ++i) {
    int v = tid + 256 * i;
    double l = (double)l0[v] + (double)l1[v] + (double)l2[v] + (double)l3[v]
             + (double)bout[v];
    double s = l - log(-log((double)ub[v]));
    sloc[i] = s;
    if (s > best) { best = s; bi = v; }   // per-thread v ascending: > = first occ.
  }
  __shared__ double sv[256];
  __shared__ int    si[256];
  __shared__ int    pre[256];
  __shared__ int    candV[CCAP_];
  __shared__ double bestS;
  __shared__ int    bestV;
  sv[tid] = best; si[tid] = bi;
  __syncthreads();
  for (int st = 128; st > 0; st >>= 1) {
    if (tid < st) {
      double ov = sv[tid + st]; int oi = si[tid + st];
      if (ov > sv[tid] || (ov == sv[tid] && oi < si[tid])) { sv[tid] = ov; si[tid] = oi; }
    }
    __syncthreads();
  }
  double smax = sv[0];
  int amax = si[0];
  __syncthreads();                     // sv/si reused below
  int c = 0; int lv[16];
#pragma unroll
  for (int i = 0; i < 16; ++i)
    if (sloc[i] >= smax - MARGIN_) { if (c < 16) lv[c] = tid + 256 * i; ++c; }
  pre[tid] = c;
  __syncthreads();
  for (int off = 1; off < 256; off <<= 1) {          // inclusive prefix scan
    int vv = (tid >= off) ? pre[tid - off] : 0;
    __syncthreads();
    pre[tid] += vv;
    __syncthreads();
  }
  int tot = pre[255];
  int base = pre[tid] - c;
  if (tot <= CCAP_)
    for (int q = 0; q < c; ++q) candV[base + q] = lv[q];
  __syncthreads();
  int tok;
  if (tot == 1) {
    tok = amax;                                       // screen error << margin
  } else if (tot <= CCAP_) {
    const float* hb = h + (size_t)b * H_;
    if (tid == 0) { bestS = -1e300; bestV = 0x7fffffff; }
    __syncthreads();
    for (int ci = 0; ci < tot; ++ci) {
      int v = candV[ci];
      const float* wr = Wout + (size_t)v * H_;
      double p = (double)hb[tid] * (double)wr[tid]
               + (double)hb[tid + 256] * (double)wr[tid + 256];
      sv[tid] = p;
      __syncthreads();
      for (int st = 128; st > 0; st >>= 1) {
        if (tid < st) sv[tid] += sv[tid + st];
        __syncthreads();
      }
      if (tid == 0) {
        double s = sv[0] + (double)bout[v] - log(-log((double)ub[v]));
        if (s > bestS || (s == bestS && v < bestV)) { bestS = s; bestV = v; }
      }
      __syncthreads();
    }
    tok = bestV;
  } else {
    // safety net: full-row fp64 rescore (statistically unreachable)
    const float* hb = h + (size_t)b * H_;
    best = -1e300; bi = 0x7fffffff;
    for (int i = 0; i < 16; ++i) {
      int v = tid + 256 * i;
      const float* wr = Wout + (size_t)v * H_;
      double dot = 0.0;
      for (int k = 0; k < H_; ++k) dot = fma((double)hb[k], (double)wr[k], dot);
      double s = dot + (double)bout[v] - log(-log((double)ub[v]));
      if (s > best) { best = s; bi = v; }
    }
    sv[tid] = best; si[tid] = bi;
    __syncthreads();
    for (int st = 128; st > 0; st >>= 1) {
      if (tid < st) {
        double ov = sv[tid + st]; int oi = si[tid + st];
        if (ov > sv[tid] || (ov == sv[tid] && oi < si[tid])) { sv[tid] = ov; si[tid] = oi; }
      }
      __syncthreads();
    }
    tok = si[0];
  }
  if (tid == 0) { toks[t * B_ + b] = tok; curTok[b] = tok; }
}

// ============== final: zero + one-hot scatter + SOS/EOS, fp32 ==============
__global__ __launch_bounds__(256) void kfinal32(float* __restrict__ out,
                                                const int* __restrict__ toks) {
  size_t c = (size_t)blockIdx.x * 256 + threadIdx.x;   // one float4
  size_t e0 = c * 4;
  int v0 = (int)(e0 & (size_t)(V_ - 1));
  size_t row = e0 >> 12;                               // b*L + p
  int p = (int)(row % L_);
  int b = (int)(row / L_);
  int tok;
  if (p == 0)           tok = 1;                       // SOS
  else if (p == L_ - 1) tok = 2;                       // EOS
  else                  tok = toks[(p - 1) * B_ + b];
  float4 val = make_float4(0.f, 0.f, 0.f, 0.f);
  int d = tok - v0;
  if (d >= 0 && d < 4) {
    if (d == 0) val.x = 1.f; else if (d == 1) val.y = 1.f;
    else if (d == 2) val.z = 1.f; else val.w = 1.f;
  }
  reinterpret_cast<float4*>(out)[c] = val;
}

// ---------------- environment markers ----------------
__global__ void kmark_ws(float* out) {
  if (threadIdx.x == 0) out[0] = 16.0f;
}
__global__ void kmark_resolver(float* out) {
  if (threadIdx.x == 0) out[2] = 11.0f;
}

// ================================ launch ================================
extern "C" void kernel_launch(void* const* d_in, const int* in_sizes, int n_in,
                              void* d_out, int out_size, void* d_ws, size_t ws_size,
                              hipStream_t stream) {
  static const int EXPECT[12] = {262144, 262144, 524288, 512, 393216, 786432,
                                 1536, 1536, 2097152, 4096, 1048576, 37748736};
  const float* R[12];
  bool resolved = (n_in == 12);
  if (resolved) {
    bool used[12] = {};
    for (int i = 0; i < 12; ++i) {
      int f = -1;
      for (int j = 0; j < 12; ++j)
        if (!used[j] && in_sizes[j] == EXPECT[i]) { f = j; break; }
      if (f < 0) { resolved = false; break; }
      used[f] = true;
      R[i] = (const float*)d_in[f];
    }
  }
  if (!resolved)
    for (int i = 0; i < 12 && i < n_in; ++i) R[i] = (const float*)d_in[i];

  const float *pa = R[0], *pb = R[1], *Winit = R[2], *binit = R[3],
              *Wih = R[4], *Whh = R[5], *bih = R[6], *bhh = R[7],
              *Wout = R[8], *bout = R[9], *emb = R[10], *ug = R[11];
  float* out = (float*)d_out;

  const size_t TOK_BYTES = (size_t)T_ * B_ * sizeof(int);   // 36864
  if (ws_size < TOK_BYTES) { kmark_ws<<<1, 64, 0, stream>>>(out); return; }
  int* toks = (int*)d_ws;

  // curTok in d_out tail (rebuilt by kfinal32 at the very end)
  size_t out_bytes = (size_t)out_size * 4;
  int* curTok = (int*)((char*)d_out + out_bytes - 2048);

  // fp32 scratch: h(1MB) | giP 2 chunks(50.3MB) | ghP 16 chunks(50.3MB)
  //               | loP 4 chunks(33.5MB)  -> 33,816,576 floats = 135.3 MB
  const size_t SC_FLOATS = 33816576;
  float* sc;
  if (ws_size >= 40960 + SC_FLOATS * sizeof(float)) {
    sc = (float*)((char*)d_ws + 40960);
  } else {
    sc = (float*)d_out;   // head of 167.8 MB out; kfinal32 rebuilds last
  }
  float* h    = sc;                         // 262,144
  float* giP  = sc + 262144;                // 12,582,912 (2 x 4096x1536)
  float* ghP  = sc + 12845056;              // 12,582,912 (16 x 512x1536)
  float* loP  = sc + 25427968;              // 8,388,608  (4 x 512x4096)
  float* cat  = loP;                        // 524,288   (pre-loop only)
  float* h0P  = loP + 524288;               // 8 x 262,144 (pre-loop only)

  // ---- setup ----
  kprep32<<<2050, 256, 0, stream>>>(pa, pb, cat, curTok);
  // h0 partials: cat[512,1024] @ Winit[512,1024]^T, split-K=8
  sgemm64<<<dim3(8, 4, 8), 256, 0, stream>>>(cat, Winit, h0P, 512, 1024, 128);
  reduceH0<<<1024, 256, 0, stream>>>(h0P, binit, h);
  // giP = emb[4096,256] @ Wih[1536,256]^T, split-K=2 (A = emb directly)
  sgemm64<<<dim3(24, 32, 2), 256, 0, stream>>>(emb, Wih, giP, 1536, 256, 128);

  // ---- decode loop ----
  for (int t = 0; t < T_; ++t) {
    // ghP = h[512,512] @ Whh[1536,512]^T, split-K=16
    sgemm64<<<dim3(24, 4, 16), 256, 0, stream>>>(h, Whh, ghP, 1536, 512, 32);
    gates32<<<1024, 256, 0, stream>>>(ghP, giP, bih, bhh, curTok, h);
    // loP = h[512,512] @ Wout[4096,512]^T, split-K=4
    sgemm64<<<dim3(64, 4, 4), 256, 0, stream>>>(h, Wout, loP, 4096, 512, 128);
    pickTok<<<512, 256, 0, stream>>>(loP, h, Wout, bout,
                                     ug + (size_t)t * B_ * V_, toks, curTok, t);
  }

  // ---- assemble fp32 output ----
  kfinal32<<<40960, 256, 0, stream>>>(out, toks);
  if (!resolved) kmark_resolver<<<1, 64, 0, stream>>>(out);
}

// Round 12
// 1323.783 us; speedup vs baseline: 5.0585x; 1.2670x over previous
//
#include <hip/hip_runtime.h>
#include <hip/hip_bf16.h>
#include <math.h>

#define B_ 512
#define E_ 256
#define H_ 512
#define V_ 4096
#define T_ 18
#define L_ 20
#define MARGIN_ 0.04
#define CCAP_ 64

typedef __attribute__((ext_vector_type(8))) short bf16x8;
typedef __attribute__((ext_vector_type(4))) float f32x4;

// ================= prep: cat fp32 + curTok=SOS =================
__global__ __launch_bounds__(256) void kprep32(const float* __restrict__ pa,
                                               const float* __restrict__ pb,
                                               float* __restrict__ cat,
                                               int* __restrict__ curTok) {
  int idx = blockIdx.x * 256 + threadIdx.x;
  if (idx < 524288) {
    int b = idx >> 10, k = idx & 1023;
    cat[idx] = (k < 512) ? pa[b * 512 + k] : pb[b * 512 + (k - 512)];
  } else {
    int b = idx - 524288;
    if (b < B_) curTok[b] = 1;   // SOS
  }
}

// ============ Wout -> bf16 (once) ============
__global__ __launch_bounds__(256) void wcvt(const float* __restrict__ W,
                                            __hip_bfloat16* __restrict__ WB) {
  int i = blockIdx.x * 256 + threadIdx.x;   // < 2097152
  WB[i] = __float2bfloat16(W[i]);
}

// ========= fp32 GEMM, 128x64 tile (MxN), 8x4/thread, split-K =========
// P[z][M,N] = A[M,K_z] @ W[N,K_z]^T  (all fp32). No bias.
__global__ __launch_bounds__(256) void sgemm64(const float* __restrict__ A,
                                               const float* __restrict__ W,
                                               float* __restrict__ P,
                                               int N, int lda, int kPer) {
  __shared__ float As[16][132];
  __shared__ float Bs[16][68];
  const int tid = threadIdx.x;
  const int tx = tid & 15, ty = tid >> 4;
  const int bn = blockIdx.x * 64, bm = blockIdx.y * 128;
  const int k0 = blockIdx.z * kPer;
  const size_t pOff = (size_t)blockIdx.z * (size_t)gridDim.y * 128 * N;
  const int kk0 = tid & 15;
  const int ra0 = (tid >> 4) * 8;
  const int cb0 = (tid >> 4) * 4;

  float acc[8][4] = {};
  for (int kb = 0; kb < kPer; kb += 16) {
#pragma unroll
    for (int q = 0; q < 8; ++q)
      As[kk0][ra0 + q] = A[(size_t)(bm + ra0 + q) * lda + k0 + kb + kk0];
#pragma unroll
    for (int q = 0; q < 4; ++q)
      Bs[kk0][cb0 + q] = W[(size_t)(bn + cb0 + q) * lda + k0 + kb + kk0];
    __syncthreads();
#pragma unroll
    for (int kk = 0; kk < 16; ++kk) {
      float a[8];
#pragma unroll
      for (int i = 0; i < 8; ++i) a[i] = As[kk][ty + 16 * i];
#pragma unroll
      for (int j = 0; j < 4; ++j) {
        float w = Bs[kk][tx + 16 * j];
#pragma unroll
        for (int i = 0; i < 8; ++i) acc[i][j] = fmaf(a[i], w, acc[i][j]);
      }
    }
    __syncthreads();
  }
#pragma unroll
  for (int i = 0; i < 8; ++i) {
    size_t r = (size_t)(bm + ty + 16 * i);
#pragma unroll
    for (int j = 0; j < 4; ++j)
      P[pOff + r * N + bn + tx + 16 * j] = acc[i][j];
  }
}

// ======== h0 = sum of 8 partials + b_init (fp64 sum); fp32 + bf16 out ======
__global__ __launch_bounds__(256) void reduceH0(const float* __restrict__ parts,
                                                const float* __restrict__ binit,
                                                float* __restrict__ h,
                                                __hip_bfloat16* __restrict__ hB) {
  int i = blockIdx.x * 256 + threadIdx.x;   // < 262144
  double s = (double)binit[i & 511];
#pragma unroll
  for (int c = 0; c < 8; ++c) s += (double)parts[(size_t)c * 262144 + i];
  float f = (float)s;
  h[i] = f;
  hB[i] = __float2bfloat16(f);
}

// ====== gates: sum 8 gh partials + gather 2 gi partials + GRU update ======
__global__ __launch_bounds__(256) void gates32(const float* __restrict__ ghP,
                                               const float* __restrict__ giP,
                                               const float* __restrict__ bih,
                                               const float* __restrict__ bhh,
                                               const int* __restrict__ curTok,
                                               float* __restrict__ h,
                                               __hip_bfloat16* __restrict__ hB) {
  int idx = blockIdx.x * 256 + threadIdx.x;   // < B_*H_
  int b = idx >> 9, j = idx & (H_ - 1);
  size_t base = (size_t)b * 1536;
  double gr = (double)bhh[j], gz = (double)bhh[512 + j], gn = (double)bhh[1024 + j];
#pragma unroll
  for (int s = 0; s < 8; ++s) {
    const float* p = ghP + (size_t)s * 786432 + base;
    gr += (double)p[j]; gz += (double)p[512 + j]; gn += (double)p[1024 + j];
  }
  const float* g0 = giP + (size_t)curTok[b] * 1536;
  const float* g1 = g0 + 6291456;
  double ir  = (double)g0[j]        + (double)g1[j]        + (double)bih[j];
  double iz  = (double)g0[512 + j]  + (double)g1[512 + j]  + (double)bih[512 + j];
  double inn = (double)g0[1024 + j] + (double)g1[1024 + j] + (double)bih[1024 + j];
  double r = 1.0 / (1.0 + exp(-(ir + gr)));
  double z = 1.0 / (1.0 + exp(-(iz + gz)));
  double n = tanh(inn + r * gn);
  float hn = (float)((1.0 - z) * n + z * (double)h[idx]);
  h[idx] = hn;
  hB[idx] = __float2bfloat16(hn);
}

// ====== bf16 MFMA screen: loP[512,4096] = hB[512,512] @ WB[4096,512]^T ======
// 16x16x32 bf16 MFMA. A: row=lane&15, k=(lane>>4)*8+i. B: col=lane&15, same k.
// D: col=lane&15, row=(lane>>4)*4+reg. Wave = 16 rows x 64 cols; block = 4 waves.
__global__ __launch_bounds__(256) void mfma_screen(const __hip_bfloat16* __restrict__ hB,
                                                   const __hip_bfloat16* __restrict__ WB,
                                                   float* __restrict__ P) {
  const int wave = threadIdx.x >> 6, lane = threadIdx.x & 63;
  const int bm = blockIdx.y * 64 + wave * 16;
  const int bn = blockIdx.x * 64;
  const int rA = lane & 15, g = lane >> 4;
  const __hip_bfloat16* ha = hB + (size_t)(bm + rA) * H_ + g * 8;
  const __hip_bfloat16* wb = WB + (size_t)(bn + rA) * H_ + g * 8;
  f32x4 acc[4] = {};
  for (int k0 = 0; k0 < H_; k0 += 32) {
    bf16x8 a = *reinterpret_cast<const bf16x8*>(ha + k0);
#pragma unroll
    for (int j = 0; j < 4; ++j) {
      bf16x8 b = *reinterpret_cast<const bf16x8*>(wb + (size_t)j * 16 * H_ + k0);
      acc[j] = __builtin_amdgcn_mfma_f32_16x16x32_bf16(a, b, acc[j], 0, 0, 0);
    }
  }
#pragma unroll
  for (int j = 0; j < 4; ++j)
#pragma unroll
    for (int r = 0; r < 4; ++r)
      P[(size_t)(bm + g * 4 + r) * V_ + bn + j * 16 + rA] = acc[j][r];
}

// ====== pickTok: screen (1 partial) + candidate-only fp64 rescore ======
__global__ __launch_bounds__(256) void pickTok(const float* __restrict__ loP,
                                               const float* __restrict__ h,
                                               const float* __restrict__ Wout,
                                               const float* __restrict__ bout,
                                               const float* __restrict__ u,  // step slice
                                               int* __restrict__ toks,
                                               int* __restrict__ curTok,
                                               int t) {
  int b = blockIdx.x, tid = threadIdx.x;
  const float* l0 = loP + (size_t)b * V_;
  const float* ub = u + (size_t)b * V_;
  double sloc[16];
  double best = -1e300; int bi = 0x7fffffff;
#pragma unroll
  for (int i = 0; i < 16; ++i) {
    int v = tid + 256 * i;
    double s = (double)l0[v] + (double)bout[v] - log(-log((double)ub[v]));
    sloc[i] = s;
    if (s > best) { best = s; bi = v; }   // per-thread v ascending: > = first occ.
  }
  __shared__ double sv[256];
  __shared__ int    si[256];
  __shared__ int    pre[256];
  __shared__ int    candV[CCAP_];
  __shared__ double bestS;
  __shared__ int    bestV;
  sv[tid] = best; si[tid] = bi;
  __syncthreads();
  for (int st = 128; st > 0; st >>= 1) {
    if (tid < st) {
      double ov = sv[tid + st]; int oi = si[tid + st];
      if (ov > sv[tid] || (ov == sv[tid] && oi < si[tid])) { sv[tid] = ov; si[tid] = oi; }
    }
    __syncthreads();
  }
  double smax = sv[0];
  int amax = si[0];
  __syncthreads();                     // sv/si reused below
  int c = 0; int lv[16];
#pragma unroll
  for (int i = 0; i < 16; ++i)
    if (sloc[i] >= smax - MARGIN_) { if (c < 16) lv[c] = tid + 256 * i; ++c; }
  pre[tid] = c;
  __syncthreads();
  for (int off = 1; off < 256; off <<= 1) {          // inclusive prefix scan
    int vv = (tid >= off) ? pre[tid - off] : 0;
    __syncthreads();
    pre[tid] += vv;
    __syncthreads();
  }
  int tot = pre[255];
  int base = pre[tid] - c;
  if (tot <= CCAP_)
    for (int q = 0; q < c; ++q) candV[base + q] = lv[q];
  __syncthreads();
  int tok;
  if (tot == 1) {
    tok = amax;                                       // screen error << margin
  } else if (tot <= CCAP_) {
    const float* hb = h + (size_t)b * H_;
    if (tid == 0) { bestS = -1e300; bestV = 0x7fffffff; }
    __syncthreads();
    for (int ci = 0; ci < tot; ++ci) {
      int v = candV[ci];
      const float* wr = Wout + (size_t)v * H_;
      double p = (double)hb[tid] * (double)wr[tid]
               + (double)hb[tid + 256] * (double)wr[tid + 256];
      sv[tid] = p;
      __syncthreads();
      for (int st = 128; st > 0; st >>= 1) {
        if (tid < st) sv[tid] += sv[tid + st];
        __syncthreads();
      }
      if (tid == 0) {
        double s = sv[0] + (double)bout[v] - log(-log((double)ub[v]));
        if (s > bestS || (s == bestS && v < bestV)) { bestS = s; bestV = v; }
      }
      __syncthreads();
    }
    tok = bestV;
  } else {
    // safety net: full-row fp64 rescore (statistically unreachable)
    const float* hb = h + (size_t)b * H_;
    best = -1e300; bi = 0x7fffffff;
    for (int i = 0; i < 16; ++i) {
      int v = tid + 256 * i;
      const float* wr = Wout + (size_t)v * H_;
      double dot = 0.0;
      for (int k = 0; k < H_; ++k) dot = fma((double)hb[k], (double)wr[k], dot);
      double s = dot + (double)bout[v] - log(-log((double)ub[v]));
      if (s > best) { best = s; bi = v; }
    }
    sv[tid] = best; si[tid] = bi;
    __syncthreads();
    for (int st = 128; st > 0; st >>= 1) {
      if (tid < st) {
        double ov = sv[tid + st]; int oi = si[tid + st];
        if (ov > sv[tid] || (ov == sv[tid] && oi < si[tid])) { sv[tid] = ov; si[tid] = oi; }
      }
      __syncthreads();
    }
    tok = si[0];
  }
  if (tid == 0) { toks[t * B_ + b] = tok; curTok[b] = tok; }
}

// ============== final: zero + one-hot scatter + SOS/EOS, fp32 ==============
__global__ __launch_bounds__(256) void kfinal32(float* __restrict__ out,
                                                const int* __restrict__ toks) {
  size_t c = (size_t)blockIdx.x * 256 + threadIdx.x;   // one float4
  size_t e0 = c * 4;
  int v0 = (int)(e0 & (size_t)(V_ - 1));
  size_t row = e0 >> 12;                               // b*L + p
  int p = (int)(row % L_);
  int b = (int)(row / L_);
  int tok;
  if (p == 0)           tok = 1;                       // SOS
  else if (p == L_ - 1) tok = 2;                       // EOS
  else                  tok = toks[(p - 1) * B_ + b];
  float4 val = make_float4(0.f, 0.f, 0.f, 0.f);
  int d = tok - v0;
  if (d >= 0 && d < 4) {
    if (d == 0) val.x = 1.f; else if (d == 1) val.y = 1.f;
    else if (d == 2) val.z = 1.f; else val.w = 1.f;
  }
  reinterpret_cast<float4*>(out)[c] = val;
}

// ---------------- environment markers ----------------
__global__ void kmark_ws(float* out) {
  if (threadIdx.x == 0) out[0] = 16.0f;
}
__global__ void kmark_resolver(float* out) {
  if (threadIdx.x == 0) out[2] = 11.0f;
}

// ================================ launch ================================
extern "C" void kernel_launch(void* const* d_in, const int* in_sizes, int n_in,
                              void* d_out, int out_size, void* d_ws, size_t ws_size,
                              hipStream_t stream) {
  static const int EXPECT[12] = {262144, 262144, 524288, 512, 393216, 786432,
                                 1536, 1536, 2097152, 4096, 1048576, 37748736};
  const float* R[12];
  bool resolved = (n_in == 12);
  if (resolved) {
    bool used[12] = {};
    for (int i = 0; i < 12; ++i) {
      int f = -1;
      for (int j = 0; j < 12; ++j)
        if (!used[j] && in_sizes[j] == EXPECT[i]) { f = j; break; }
      if (f < 0) { resolved = false; break; }
      used[f] = true;
      R[i] = (const float*)d_in[f];
    }
  }
  if (!resolved)
    for (int i = 0; i < 12 && i < n_in; ++i) R[i] = (const float*)d_in[i];

  const float *pa = R[0], *pb = R[1], *Winit = R[2], *binit = R[3],
              *Wih = R[4], *Whh = R[5], *bih = R[6], *bhh = R[7],
              *Wout = R[8], *bout = R[9], *emb = R[10], *ug = R[11];
  float* out = (float*)d_out;

  const size_t TOK_BYTES = (size_t)T_ * B_ * sizeof(int);   // 36864
  if (ws_size < TOK_BYTES) { kmark_ws<<<1, 64, 0, stream>>>(out); return; }
  int* toks = (int*)d_ws;

  // curTok in d_out tail (rebuilt by kfinal32 at the very end)
  size_t out_bytes = (size_t)out_size * 4;
  int* curTok = (int*)((char*)d_out + out_bytes - 2048);

  // fp32-equivalent scratch layout (22,413,312 floats = 89.7 MB):
  //  h | giP(2 chunks) | ghP(8 chunks, aliases cat+h0P pre-loop) | loP | hB | WoutB
  const size_t SC_FLOATS = 22413312;
  float* sc;
  if (ws_size >= 40960 + SC_FLOATS * sizeof(float)) {
    sc = (float*)((char*)d_ws + 40960);
  } else {
    sc = (float*)d_out;   // head of 167.8 MB out; kfinal32 rebuilds last
  }
  float* h    = sc;                                   // 262,144
  float* giP  = sc + 262144;                          // 12,582,912 (2 x 4096x1536)
  float* ghP  = sc + 12845056;                        // 6,291,456  (8 x 512x1536)
  float* loP  = sc + 19136512;                        // 2,097,152  (512x4096)
  __hip_bfloat16* hB    = (__hip_bfloat16*)(sc + 21233664);   // 262,144 bf16
  __hip_bfloat16* WoutB = (__hip_bfloat16*)(sc + 21364736);   // 2,097,152 bf16
  float* cat  = ghP;                                  // 524,288   (pre-loop only)
  float* h0P  = ghP + 524288;                         // 8 x 262,144 (pre-loop only)

  // ---- setup ----
  kprep32<<<2050, 256, 0, stream>>>(pa, pb, cat, curTok);
  wcvt<<<8192, 256, 0, stream>>>(Wout, WoutB);
  // h0 partials: cat[512,1024] @ Winit[512,1024]^T, split-K=8
  sgemm64<<<dim3(8, 4, 8), 256, 0, stream>>>(cat, Winit, h0P, 512, 1024, 128);
  reduceH0<<<1024, 256, 0, stream>>>(h0P, binit, h, hB);
  // giP = emb[4096,256] @ Wih[1536,256]^T, split-K=2
  sgemm64<<<dim3(24, 32, 2), 256, 0, stream>>>(emb, Wih, giP, 1536, 256, 128);

  // ---- decode loop ----
  for (int t = 0; t < T_; ++t) {
    // ghP = h[512,512] @ Whh[1536,512]^T, split-K=8
    sgemm64<<<dim3(24, 4, 8), 256, 0, stream>>>(h, Whh, ghP, 1536, 512, 64);
    gates32<<<1024, 256, 0, stream>>>(ghP, giP, bih, bhh, curTok, h, hB);
    // loP = hB @ WoutB^T via bf16 MFMA (margin-protected screen)
    mfma_screen<<<dim3(64, 8), 256, 0, stream>>>(hB, WoutB, loP);
    pickTok<<<512, 256, 0, stream>>>(loP, h, Wout, bout,
                                     ug + (size_t)t * B_ * V_, toks, curTok, t);
  }

  // ---- assemble fp32 output ----
  kfinal32<<<40960, 256, 0, stream>>>(out, toks);
  if (!resolved) kmark_resolver<<<1, 64, 0, stream>>>(out);
}

// Round 13
// 1195.678 us; speedup vs baseline: 5.6005x; 1.1071x over previous
//
#include <hip/hip_runtime.h>
#include <hip/hip_bf16.h>
#include <math.h>

#define B_ 512
#define E_ 256
#define H_ 512
#define V_ 4096
#define T_ 18
#define L_ 20
#define MARGIN_ 0.04f
#define CCAP_ 64

typedef __attribute__((ext_vector_type(8))) short bf16x8;
typedef __attribute__((ext_vector_type(4))) float f32x4;

// ================= prep: cat fp32 + curTok=SOS =================
__global__ __launch_bounds__(256) void kprep32(const float* __restrict__ pa,
                                               const float* __restrict__ pb,
                                               float* __restrict__ cat,
                                               int* __restrict__ curTok) {
  int idx = blockIdx.x * 256 + threadIdx.x;
  if (idx < 524288) {
    int b = idx >> 10, k = idx & 1023;
    cat[idx] = (k < 512) ? pa[b * 512 + k] : pb[b * 512 + (k - 512)];
  } else {
    int b = idx - 524288;
    if (b < B_) curTok[b] = 1;   // SOS
  }
}

// ============ Wout -> bf16 (once) ============
__global__ __launch_bounds__(256) void wcvt(const float* __restrict__ W,
                                            __hip_bfloat16* __restrict__ WB) {
  int i = blockIdx.x * 256 + threadIdx.x;   // < 2097152
  WB[i] = __float2bfloat16(W[i]);
}

// ===== fp32 GEMM, 128x128 tile, 8x8/thread, split-K (0.75 B/FMA LDS) =====
// P[z][M,N] = A[M,K_z] @ W[N,K_z]^T. grid (N/128, M/128, S); kPer = K/S.
__global__ __launch_bounds__(256) void sgemm128(const float* __restrict__ A,
                                                const float* __restrict__ W,
                                                float* __restrict__ P,
                                                int N, int lda, int kPer) {
  __shared__ float As[16][132];
  __shared__ float Bs[16][132];
  const int tid = threadIdx.x;
  const int tx = tid & 15, ty = tid >> 4;
  const int bn = blockIdx.x * 128, bm = blockIdx.y * 128;
  const int k0 = blockIdx.z * kPer;
  const size_t pOff = (size_t)blockIdx.z * (size_t)gridDim.y * 128 * N;
  const int kk0 = tid & 15;
  const int r0 = (tid >> 4) * 8;

  float acc[8][8] = {};
  for (int kb = 0; kb < kPer; kb += 16) {
#pragma unroll
    for (int q = 0; q < 8; ++q) {
      As[kk0][r0 + q] = A[(size_t)(bm + r0 + q) * lda + k0 + kb + kk0];
      Bs[kk0][r0 + q] = W[(size_t)(bn + r0 + q) * lda + k0 + kb + kk0];
    }
    __syncthreads();
#pragma unroll
    for (int kk = 0; kk < 16; ++kk) {
      float a[8], b[8];
#pragma unroll
      for (int i = 0; i < 8; ++i) a[i] = As[kk][ty + 16 * i];
#pragma unroll
      for (int j = 0; j < 8; ++j) b[j] = Bs[kk][tx + 16 * j];
#pragma unroll
      for (int i = 0; i < 8; ++i)
#pragma unroll
        for (int j = 0; j < 8; ++j) acc[i][j] = fmaf(a[i], b[j], acc[i][j]);
    }
    __syncthreads();
  }
#pragma unroll
  for (int i = 0; i < 8; ++i) {
    size_t r = (size_t)(bm + ty + 16 * i);
#pragma unroll
    for (int j = 0; j < 8; ++j)
      P[pOff + r * N + bn + tx + 16 * j] = acc[i][j];
  }
}

// ======== h0 = sum of 8 partials + b_init (fp64 sum); fp32 + bf16 out ======
__global__ __launch_bounds__(256) void reduceH0(const float* __restrict__ parts,
                                                const float* __restrict__ binit,
                                                float* __restrict__ h,
                                                __hip_bfloat16* __restrict__ hB) {
  int i = blockIdx.x * 256 + threadIdx.x;   // < 262144
  double s = (double)binit[i & 511];
#pragma unroll
  for (int c = 0; c < 8; ++c) s += (double)parts[(size_t)c * 262144 + i];
  float f = (float)s;
  h[i] = f;
  hB[i] = __float2bfloat16(f);
}

// ====== gates: sum 8 gh partials + gather gi + GRU update (fp32 gates) ======
__global__ __launch_bounds__(256) void gates32(const float* __restrict__ ghP,
                                               const float* __restrict__ giP,
                                               const float* __restrict__ bih,
                                               const float* __restrict__ bhh,
                                               const int* __restrict__ curTok,
                                               float* __restrict__ h,
                                               __hip_bfloat16* __restrict__ hB) {
  int idx = blockIdx.x * 256 + threadIdx.x;   // < B_*H_
  int b = idx >> 9, j = idx & (H_ - 1);
  size_t base = (size_t)b * 1536;
  double gr = (double)bhh[j], gz = (double)bhh[512 + j], gn = (double)bhh[1024 + j];
#pragma unroll
  for (int s = 0; s < 8; ++s) {
    const float* p = ghP + (size_t)s * 786432 + base;
    gr += (double)p[j]; gz += (double)p[512 + j]; gn += (double)p[1024 + j];
  }
  const float* g0 = giP + (size_t)curTok[b] * 1536;
  float ir  = g0[j]        + bih[j];
  float iz  = g0[512 + j]  + bih[512 + j];
  float inn = g0[1024 + j] + bih[1024 + j];
  float r = 1.f / (1.f + expf(-(ir + (float)gr)));
  float z = 1.f / (1.f + expf(-(iz + (float)gz)));
  float n = tanhf(inn + r * (float)gn);
  float hn = (1.f - z) * n + z * h[idx];
  h[idx] = hn;
  hB[idx] = __float2bfloat16(hn);
}

// ====== bf16 MFMA screen: loP[512,4096] = hB[512,512] @ WB[4096,512]^T ======
__global__ __launch_bounds__(256) void mfma_screen(const __hip_bfloat16* __restrict__ hB,
                                                   const __hip_bfloat16* __restrict__ WB,
                                                   float* __restrict__ P) {
  const int wave = threadIdx.x >> 6, lane = threadIdx.x & 63;
  const int bm = blockIdx.y * 64 + wave * 16;
  const int bn = blockIdx.x * 64;
  const int rA = lane & 15, g = lane >> 4;
  const __hip_bfloat16* ha = hB + (size_t)(bm + rA) * H_ + g * 8;
  const __hip_bfloat16* wb = WB + (size_t)(bn + rA) * H_ + g * 8;
  f32x4 acc[4] = {};
  for (int k0 = 0; k0 < H_; k0 += 32) {
    bf16x8 a = *reinterpret_cast<const bf16x8*>(ha + k0);
#pragma unroll
    for (int j = 0; j < 4; ++j) {
      bf16x8 b = *reinterpret_cast<const bf16x8*>(wb + (size_t)j * 16 * H_ + k0);
      acc[j] = __builtin_amdgcn_mfma_f32_16x16x32_bf16(a, b, acc[j], 0, 0, 0);
    }
  }
#pragma unroll
  for (int j = 0; j < 4; ++j)
#pragma unroll
    for (int r = 0; r < 4; ++r)
      P[(size_t)(bm + g * 4 + r) * V_ + bn + j * 16 + rA] = acc[j][r];
}

// ====== pickTok: fp32 screen + candidate-only fp64 rescore ======
__global__ __launch_bounds__(256) void pickTok(const float* __restrict__ loP,
                                               const float* __restrict__ h,
                                               const float* __restrict__ Wout,
                                               const float* __restrict__ bout,
                                               const float* __restrict__ u,  // step slice
                                               int* __restrict__ toks,
                                               int* __restrict__ curTok,
                                               int t) {
  int b = blockIdx.x, tid = threadIdx.x;
  const float* l0 = loP + (size_t)b * V_;
  const float* ub = u + (size_t)b * V_;
  float sloc[16];
  float best = -1e30f; int bi = 0x7fffffff;
#pragma unroll
  for (int i = 0; i < 16; ++i) {
    int v = tid + 256 * i;
    float s = l0[v] + bout[v] - logf(-logf(ub[v]));   // fp32 screen score
    sloc[i] = s;
    if (s > best) { best = s; bi = v; }   // per-thread v ascending: > = first occ.
  }
  __shared__ float  sv[256];
  __shared__ int    si[256];
  __shared__ int    pre[256];
  __shared__ int    candV[CCAP_];
  __shared__ double sd[256];
  __shared__ double bestS;
  __shared__ int    bestV;
  sv[tid] = best; si[tid] = bi;
  __syncthreads();
  for (int st = 128; st > 0; st >>= 1) {
    if (tid < st) {
      float ov = sv[tid + st]; int oi = si[tid + st];
      if (ov > sv[tid] || (ov == sv[tid] && oi < si[tid])) { sv[tid] = ov; si[tid] = oi; }
    }
    __syncthreads();
  }
  float smax = sv[0];
  int amax = si[0];
  __syncthreads();
  int c = 0; int lv[16];
#pragma unroll
  for (int i = 0; i < 16; ++i)
    if (sloc[i] >= smax - MARGIN_) { if (c < 16) lv[c] = tid + 256 * i; ++c; }
  pre[tid] = c;
  __syncthreads();
  for (int off = 1; off < 256; off <<= 1) {          // inclusive prefix scan
    int vv = (tid >= off) ? pre[tid - off] : 0;
    __syncthreads();
    pre[tid] += vv;
    __syncthreads();
  }
  int tot = pre[255];
  int base = pre[tid] - c;
  if (tot <= CCAP_)
    for (int q = 0; q < c; ++q) candV[base + q] = lv[q];
  __syncthreads();
  int tok;
  if (tot == 1) {
    tok = amax;                                       // screen error << margin
  } else if (tot <= CCAP_) {
    const float* hb = h + (size_t)b * H_;
    if (tid == 0) { bestS = -1e300; bestV = 0x7fffffff; }
    __syncthreads();
    for (int ci = 0; ci < tot; ++ci) {
      int v = candV[ci];
      const float* wr = Wout + (size_t)v * H_;
      double p = (double)hb[tid] * (double)wr[tid]
               + (double)hb[tid + 256] * (double)wr[tid + 256];
      sd[tid] = p;
      __syncthreads();
      for (int st = 128; st > 0; st >>= 1) {
        if (tid < st) sd[tid] += sd[tid + st];
        __syncthreads();
      }
      if (tid == 0) {
        double s = sd[0] + (double)bout[v] - log(-log((double)ub[v]));
        if (s > bestS || (s == bestS && v < bestV)) { bestS = s; bestV = v; }
      }
      __syncthreads();
    }
    tok = bestV;
  } else {
    // safety net: full-row fp64 rescore (statistically unreachable)
    const float* hb = h + (size_t)b * H_;
    double dbest = -1e300; bi = 0x7fffffff;
    for (int i = 0; i < 16; ++i) {
      int v = tid + 256 * i;
      const float* wr = Wout + (size_t)v * H_;
      double dot = 0.0;
      for (int k = 0; k < H_; ++k) dot = fma((double)hb[k], (double)wr[k], dot);
      double s = dot + (double)bout[v] - log(-log((double)ub[v]));
      if (s > dbest) { dbest = s; bi = v; }
    }
    sd[tid] = dbest; si[tid] = bi;
    __syncthreads();
    for (int st = 128; st > 0; st >>= 1) {
      if (tid < st) {
        double ov = sd[tid + st]; int oi = si[tid + st];
        if (ov > sd[tid] || (ov == sd[tid] && oi < si[tid])) { sd[tid] = ov; si[tid] = oi; }
      }
      __syncthreads();
    }
    tok = si[0];
  }
  if (tid == 0) { toks[t * B_ + b] = tok; curTok[b] = tok; }
}

// ============== final: zero + one-hot scatter + SOS/EOS, fp32 ==============
__global__ __launch_bounds__(256) void kfinal32(float* __restrict__ out,
                                                const int* __restrict__ toks) {
  size_t c = (size_t)blockIdx.x * 256 + threadIdx.x;   // one float4
  size_t e0 = c * 4;
  int v0 = (int)(e0 & (size_t)(V_ - 1));
  size_t row = e0 >> 12;                               // b*L + p
  int p = (int)(row % L_);
  int b = (int)(row / L_);
  int tok;
  if (p == 0)           tok = 1;                       // SOS
  else if (p == L_ - 1) tok = 2;                       // EOS
  else                  tok = toks[(p - 1) * B_ + b];
  float4 val = make_float4(0.f, 0.f, 0.f, 0.f);
  int d = tok - v0;
  if (d >= 0 && d < 4) {
    if (d == 0) val.x = 1.f; else if (d == 1) val.y = 1.f;
    else if (d == 2) val.z = 1.f; else val.w = 1.f;
  }
  reinterpret_cast<float4*>(out)[c] = val;
}

// ---------------- environment markers ----------------
__global__ void kmark_ws(float* out) {
  if (threadIdx.x == 0) out[0] = 16.0f;
}
__global__ void kmark_resolver(float* out) {
  if (threadIdx.x == 0) out[2] = 11.0f;
}

// ================================ launch ================================
extern "C" void kernel_launch(void* const* d_in, const int* in_sizes, int n_in,
                              void* d_out, int out_size, void* d_ws, size_t ws_size,
                              hipStream_t stream) {
  static const int EXPECT[12] = {262144, 262144, 524288, 512, 393216, 786432,
                                 1536, 1536, 2097152, 4096, 1048576, 37748736};
  const float* R[12];
  bool resolved = (n_in == 12);
  if (resolved) {
    bool used[12] = {};
    for (int i = 0; i < 12; ++i) {
      int f = -1;
      for (int j = 0; j < 12; ++j)
        if (!used[j] && in_sizes[j] == EXPECT[i]) { f = j; break; }
      if (f < 0) { resolved = false; break; }
      used[f] = true;
      R[i] = (const float*)d_in[f];
    }
  }
  if (!resolved)
    for (int i = 0; i < 12 && i < n_in; ++i) R[i] = (const float*)d_in[i];

  const float *pa = R[0], *pb = R[1], *Winit = R[2], *binit = R[3],
              *Wih = R[4], *Whh = R[5], *bih = R[6], *bhh = R[7],
              *Wout = R[8], *bout = R[9], *emb = R[10], *ug = R[11];
  float* out = (float*)d_out;

  const size_t TOK_BYTES = (size_t)T_ * B_ * sizeof(int);   // 36864
  if (ws_size < TOK_BYTES) { kmark_ws<<<1, 64, 0, stream>>>(out); return; }
  int* toks = (int*)d_ws;

  // curTok in d_out tail (rebuilt by kfinal32 at the very end)
  size_t out_bytes = (size_t)out_size * 4;
  int* curTok = (int*)((char*)d_out + out_bytes - 2048);

  // scratch (fp32-equivalent units, 16,121,856 floats = 64.5 MB):
  //  h | giP(1 chunk) | ghP(8 chunks, aliases cat+h0P pre-loop) | loP | hB | WoutB
  const size_t SC_FLOATS = 16121856;
  float* sc;
  if (ws_size >= 40960 + SC_FLOATS * sizeof(float)) {
    sc = (float*)((char*)d_ws + 40960);
  } else {
    sc = (float*)d_out;   // head of 167.8 MB out; kfinal32 rebuilds last
  }
  float* h    = sc;                                   // 262,144
  float* giP  = sc + 262144;                          // 6,291,456 (4096x1536)
  float* ghP  = sc + 6553600;                         // 6,291,456 (8 x 512x1536)
  float* loP  = sc + 12845056;                        // 2,097,152 (512x4096)
  __hip_bfloat16* hB    = (__hip_bfloat16*)(sc + 14942208);   // 262,144 bf16
  __hip_bfloat16* WoutB = (__hip_bfloat16*)(sc + 15073280);   // 2,097,152 bf16
  float* cat  = ghP;                                  // 524,288   (pre-loop only)
  float* h0P  = ghP + 524288;                         // 8 x 262,144 (pre-loop only)

  // ---- setup ----
  kprep32<<<2050, 256, 0, stream>>>(pa, pb, cat, curTok);
  wcvt<<<8192, 256, 0, stream>>>(Wout, WoutB);
  // h0 partials: cat[512,1024] @ Winit[512,1024]^T, split-K=8
  sgemm128<<<dim3(4, 4, 8), 256, 0, stream>>>(cat, Winit, h0P, 512, 1024, 128);
  reduceH0<<<1024, 256, 0, stream>>>(h0P, binit, h, hB);
  // giP = emb[4096,256] @ Wih[1536,256]^T, single chunk
  sgemm128<<<dim3(12, 32, 1), 256, 0, stream>>>(emb, Wih, giP, 1536, 256, 256);

  // ---- decode loop ----
  for (int t = 0; t < T_; ++t) {
    // ghP = h[512,512] @ Whh[1536,512]^T, split-K=8
    sgemm128<<<dim3(12, 4, 8), 256, 0, stream>>>(h, Whh, ghP, 1536, 512, 64);
    gates32<<<1024, 256, 0, stream>>>(ghP, giP, bih, bhh, curTok, h, hB);
    // loP = hB @ WoutB^T via bf16 MFMA (margin-protected screen)
    mfma_screen<<<dim3(64, 8), 256, 0, stream>>>(hB, WoutB, loP);
    pickTok<<<512, 256, 0, stream>>>(loP, h, Wout, bout,
                                     ug + (size_t)t * B_ * V_, toks, curTok, t);
  }

  // ---- assemble fp32 output ----
  kfinal32<<<40960, 256, 0, stream>>>(out, toks);
  if (!resolved) kmark_resolver<<<1, 64, 0, stream>>>(out);
}